// Round 1
// baseline (2608.194 us; speedup 1.0000x reference)
//
#include <hip/hip_runtime.h>

// Problem constants (fixed by reference setup_inputs)
constexpr int Bc = 4;
constexpr int Nc = 50000;
constexpr int Kc = 10;
constexpr int Fc = 128;
constexpr int Hc = 16;
constexpr int Cc = 64;                    // 4*H output channels
constexpr int NODES = Bc * Nc;            // 200000
constexpr int PAIRS = NODES / 2;          // 100000
constexpr int TOTAL_THREADS = PAIRS * 4;  // 4 head-quadrants per node pair
constexpr int BLK = 256;

__global__ __launch_bounds__(BLK)
void gat_kernel(const float* __restrict__ x,
                const float* __restrict__ W,
                const float* __restrict__ a,
                float* __restrict__ out)
{
    const int g = blockIdx.x * BLK + threadIdx.x;
    if (g >= TOTAL_THREADS) return;

    const int q    = g & 3;   // head quadrant: heads 4q..4q+3, cols 16q..16q+15
    const int pair = g >> 2;
    const int n0   = pair * 2;  // flat node index (same batch for n0, n0+1 since N even)

    const float* xr0 = x + (size_t)n0 * (Kc * Fc);
    const float* xr1 = xr0 + (Kc * Fc);

    // attention coefficients for my 4 heads: ar[h][d] = a[d][4q+h]
    float ar[4][4];
#pragma unroll
    for (int h = 0; h < 4; ++h)
#pragma unroll
        for (int d = 0; d < 4; ++d)
            ar[h][d] = a[d * Hc + (q * 4 + h)];

    float acc0[16], acc1[16];
    float m0[4], m1[4], l0[4], l1[4];
#pragma unroll
    for (int i = 0; i < 16; ++i) { acc0[i] = 0.f; acc1[i] = 0.f; }
#pragma unroll
    for (int h = 0; h < 4; ++h) {
        m0[h] = -1e30f; m1[h] = -1e30f;
        l0[h] = 0.f;    l1[h] = 0.f;
    }

    for (int k = 0; k < Kc; ++k) {
        const float4* xk0 = reinterpret_cast<const float4*>(xr0 + k * Fc);
        const float4* xk1 = reinterpret_cast<const float4*>(xr1 + k * Fc);

#pragma unroll
        for (int h = 0; h < 4; ++h) {
            const float* Wc = W + (q * 16 + h * 4);  // column base for this head
            float hwa[4] = {0.f, 0.f, 0.f, 0.f};
            float hwb[4] = {0.f, 0.f, 0.f, 0.f};

#pragma unroll 4
            for (int f4 = 0; f4 < Fc / 4; ++f4) {
                const float4 xa = xk0[f4];
                const float4 xb = xk1[f4];
#pragma unroll
                for (int j = 0; j < 4; ++j) {
                    const float4 w = *reinterpret_cast<const float4*>(Wc + (size_t)(f4 * 4 + j) * Cc);
                    const float xs0 = (&xa.x)[j];
                    const float xs1 = (&xb.x)[j];
                    hwa[0] = fmaf(xs0, w.x, hwa[0]);
                    hwa[1] = fmaf(xs0, w.y, hwa[1]);
                    hwa[2] = fmaf(xs0, w.z, hwa[2]);
                    hwa[3] = fmaf(xs0, w.w, hwa[3]);
                    hwb[0] = fmaf(xs1, w.x, hwb[0]);
                    hwb[1] = fmaf(xs1, w.y, hwb[1]);
                    hwb[2] = fmaf(xs1, w.z, hwb[2]);
                    hwb[3] = fmaf(xs1, w.w, hwb[3]);
                }
            }

            // logits
            const float lg0 = fmaf(hwa[0], ar[h][0],
                             fmaf(hwa[1], ar[h][1],
                             fmaf(hwa[2], ar[h][2], hwa[3] * ar[h][3])));
            const float lg1 = fmaf(hwb[0], ar[h][0],
                             fmaf(hwb[1], ar[h][1],
                             fmaf(hwb[2], ar[h][2], hwb[3] * ar[h][3])));

            // online softmax update (node 0)
            {
                const float mn = fmaxf(m0[h], lg0);
                const float s  = __expf(m0[h] - mn);
                const float p  = __expf(lg0 - mn);
                m0[h] = mn;
                l0[h] = fmaf(l0[h], s, p);
#pragma unroll
                for (int d = 0; d < 4; ++d)
                    acc0[4 * h + d] = fmaf(acc0[4 * h + d], s, p * hwa[d]);
            }
            // online softmax update (node 1)
            {
                const float mn = fmaxf(m1[h], lg1);
                const float s  = __expf(m1[h] - mn);
                const float p  = __expf(lg1 - mn);
                m1[h] = mn;
                l1[h] = fmaf(l1[h], s, p);
#pragma unroll
                for (int d = 0; d < 4; ++d)
                    acc1[4 * h + d] = fmaf(acc1[4 * h + d], s, p * hwb[d]);
            }
        }
    }

    // epilogue: divide, leaky-relu, store transposed [B, 64, N]
    const int b   = n0 / Nc;
    const int nn0 = n0 - b * Nc;
    float* ob = out + (size_t)b * Cc * Nc + nn0;

#pragma unroll
    for (int h = 0; h < 4; ++h) {
        const float inv0 = 1.0f / l0[h];
        const float inv1 = 1.0f / l1[h];
#pragma unroll
        for (int d = 0; d < 4; ++d) {
            float v0 = acc0[4 * h + d] * inv0;
            float v1 = acc1[4 * h + d] * inv1;
            v0 = fmaxf(v0, 0.2f * v0);  // leaky_relu slope 0.2
            v1 = fmaxf(v1, 0.2f * v1);
            const size_t co = (size_t)(q * 16 + h * 4 + d) * Nc;
            ob[co]     = v0;
            ob[co + 1] = v1;
        }
    }
}

extern "C" void kernel_launch(void* const* d_in, const int* in_sizes, int n_in,
                              void* d_out, int out_size, void* d_ws, size_t ws_size,
                              hipStream_t stream) {
    const float* x = (const float*)d_in[0];
    const float* W = (const float*)d_in[1];
    const float* a = (const float*)d_in[2];
    float* out = (float*)d_out;

    const int grid = (TOTAL_THREADS + BLK - 1) / BLK;
    gat_kernel<<<grid, BLK, 0, stream>>>(x, W, a, out);
}

// Round 2
// 625.250 us; speedup vs baseline: 4.1714x; 4.1714x over previous
//
#include <hip/hip_runtime.h>

// Problem constants (fixed by reference setup_inputs)
constexpr int Bc = 4;
constexpr int Nc = 50000;
constexpr int Kc = 10;
constexpr int Fc = 128;
constexpr int Hc = 16;
constexpr int Cc = 64;          // 4*H output channels
constexpr int NODES = Bc * Nc;  // 200000
constexpr int NPB = 16;         // nodes per block (50000 % 16 == 0 -> no batch straddle)
constexpr int BLK = 256;        // 16 nodes x 16 heads

__global__ __launch_bounds__(BLK)
void gat_kernel(const float* __restrict__ x,
                const float* __restrict__ W,
                const float* __restrict__ a,
                float* __restrict__ out)
{
    __shared__ float Wl[Fc * Cc];   // 32 KB, same [f][c] layout as global
    __shared__ float ol[NPB][68];   // out staging, padded row (68*4B, 16B-aligned rows)

    // ---- stage W into LDS, fully coalesced (8 float4 per thread) ----
    {
        const float4* Wg = reinterpret_cast<const float4*>(W);
        float4* Wd = reinterpret_cast<float4*>(Wl);
#pragma unroll
        for (int i = 0; i < (Fc * Cc / 4) / BLK; ++i)
            Wd[threadIdx.x + i * BLK] = Wg[threadIdx.x + i * BLK];
    }
    __syncthreads();

    const int tid  = threadIdx.x;
    const int h    = tid & (Hc - 1);  // head 0..15 (lanes 0-15 share a node -> broadcast x loads)
    const int ln   = tid >> 4;        // local node 0..15
    const int node = blockIdx.x * NPB + ln;

    const float* xr = x + (size_t)node * (Kc * Fc);

    // attention coefficients for my head
    const float ar0 = a[0 * Hc + h];
    const float ar1 = a[1 * Hc + h];
    const float ar2 = a[2 * Hc + h];
    const float ar3 = a[3 * Hc + h];

    // hw[k][d] kept live across the whole f reduction (W read exactly once)
    float hw[Kc][4];
#pragma unroll
    for (int k = 0; k < Kc; ++k) {
        hw[k][0] = 0.f; hw[k][1] = 0.f; hw[k][2] = 0.f; hw[k][3] = 0.f;
    }

    const float* wb = Wl + h * 4;  // my head's 4 columns

#pragma unroll 4
    for (int f4 = 0; f4 < Fc / 4; ++f4) {
        // issue all 10 x loads up front (16-way broadcast within node group)
        float4 xv[Kc];
#pragma unroll
        for (int k = 0; k < Kc; ++k)
            xv[k] = *reinterpret_cast<const float4*>(xr + k * Fc + f4 * 4);

#pragma unroll
        for (int j = 0; j < 4; ++j) {
            const float4 w = *reinterpret_cast<const float4*>(wb + (size_t)(f4 * 4 + j) * Cc);
#pragma unroll
            for (int k = 0; k < Kc; ++k) {
                const float xs = (&xv[k].x)[j];
                hw[k][0] = fmaf(xs, w.x, hw[k][0]);
                hw[k][1] = fmaf(xs, w.y, hw[k][1]);
                hw[k][2] = fmaf(xs, w.z, hw[k][2]);
                hw[k][3] = fmaf(xs, w.w, hw[k][3]);
            }
        }
    }

    // ---- softmax over the K=10 neighbors (all logits in regs) ----
    float lg[Kc];
    float mx = -1e30f;
#pragma unroll
    for (int k = 0; k < Kc; ++k) {
        lg[k] = fmaf(hw[k][0], ar0,
                fmaf(hw[k][1], ar1,
                fmaf(hw[k][2], ar2, hw[k][3] * ar3)));
        mx = fmaxf(mx, lg[k]);
    }
    float l = 0.f;
    float o0 = 0.f, o1 = 0.f, o2 = 0.f, o3 = 0.f;
#pragma unroll
    for (int k = 0; k < Kc; ++k) {
        const float p = __expf(lg[k] - mx);
        l += p;
        o0 = fmaf(p, hw[k][0], o0);
        o1 = fmaf(p, hw[k][1], o1);
        o2 = fmaf(p, hw[k][2], o2);
        o3 = fmaf(p, hw[k][3], o3);
    }
    const float inv = 1.f / l;
    o0 *= inv; o1 *= inv; o2 *= inv; o3 *= inv;
    // leaky_relu slope 0.2
    o0 = fmaxf(o0, 0.2f * o0);
    o1 = fmaxf(o1, 0.2f * o1);
    o2 = fmaxf(o2, 0.2f * o2);
    o3 = fmaxf(o3, 0.2f * o3);

    // ---- block-wide transpose through LDS for coalesced [B,64,N] store ----
    *reinterpret_cast<float4*>(&ol[ln][h * 4]) = make_float4(o0, o1, o2, o3);
    __syncthreads();

    const int c  = tid >> 2;   // channel 0..63
    const int nc = tid & 3;    // node quad 0..3
    const int nb = blockIdx.x * NPB;
    const int b  = nb / Nc;
    const int n0 = nb - b * Nc;

    float4 v;
    v.x = ol[nc * 4 + 0][c];
    v.y = ol[nc * 4 + 1][c];
    v.z = ol[nc * 4 + 2][c];
    v.w = ol[nc * 4 + 3][c];
    *reinterpret_cast<float4*>(out + ((size_t)b * Cc + c) * Nc + n0 + nc * 4) = v;
}

extern "C" void kernel_launch(void* const* d_in, const int* in_sizes, int n_in,
                              void* d_out, int out_size, void* d_ws, size_t ws_size,
                              hipStream_t stream) {
    const float* x = (const float*)d_in[0];
    const float* W = (const float*)d_in[1];
    const float* a = (const float*)d_in[2];
    float* out = (float*)d_out;

    const int grid = NODES / NPB;  // 12500
    gat_kernel<<<grid, BLK, 0, stream>>>(x, W, a, out);
}

// Round 3
// 233.620 us; speedup vs baseline: 11.1642x; 2.6764x over previous
//
#include <hip/hip_runtime.h>

typedef short bf16x8 __attribute__((ext_vector_type(8)));
typedef float f32x4 __attribute__((ext_vector_type(4)));

// Problem constants (fixed by reference setup_inputs)
constexpr int Bc = 4;
constexpr int Nc = 50000;
constexpr int Kc = 10;
constexpr int Fc = 128;
constexpr int Hc = 16;
constexpr int Cc = 64;            // 4*H output channels
constexpr int NODES = Bc * Nc;    // 200000
constexpr int NPB = 8;            // nodes per block (50000 % 8 == 0 -> no batch straddle)
constexpr int ROWS = NPB * Kc;    // 80 GEMM rows per block
constexpr int MT = ROWS / 16;     // 5 M-tiles
constexpr int BLK = 256;          // 4 waves

// LDS layout (phases alias):
//  phase A/B: xl bf16 [80][128], swizzled, 256 B rows   -> bytes [0, 20480)
//             Wt bf16 [64][128], swizzled, 256 B rows   -> bytes [20480, 36864)
//  phase C/D: hw  f32 [80][68]                          -> bytes [0, 21760)
//             ol  f32 [8][68]                           -> bytes [21760, 23936)
constexpr int LDS_BYTES = 36864;
constexpr int WT_OFF = 20480;
constexpr int OL_OFF = 21760;

__device__ __forceinline__ unsigned short f2bf(float f) {
    // round-to-nearest-even fp32 -> bf16
    unsigned u = __builtin_bit_cast(unsigned, f);
    return (unsigned short)((u + 0x7fffu + ((u >> 16) & 1u)) >> 16);
}

// One-block prep: W [128][64] f32 -> Wt [64][128] bf16 in d_ws, LDS swizzle pre-baked
// (element index: c*128 + (f ^ ((c&7)<<3)) which equals byte addr c*256 + (2f ^ ((c&7)<<4))).
__global__ __launch_bounds__(256)
void prep_w(const float* __restrict__ W, unsigned short* __restrict__ wt) {
    const int t = threadIdx.x;
#pragma unroll
    for (int i = 0; i < 32; ++i) {
        const int flat = t + i * 256;       // 8192 = 128*64, flat indexes [f][c]
        const int c = flat & 63;
        const int f = flat >> 6;
        wt[c * 128 + (f ^ ((c & 7) << 3))] = f2bf(W[flat]);
    }
}

__global__ __launch_bounds__(BLK)
void gat_kernel(const float* __restrict__ x,
                const unsigned short* __restrict__ wt_ws,
                const float* __restrict__ a,
                float* __restrict__ out)
{
    __shared__ __align__(16) char smem[LDS_BYTES];

    const int t = threadIdx.x;

    // ---- phase A: stage x (fp32 -> bf16, swizzled) and Wt (pre-swizzled copy) ----
    {
        const float4* xg = reinterpret_cast<const float4*>(x + (size_t)blockIdx.x * (ROWS * Fc));
#pragma unroll
        for (int i = 0; i < (ROWS * Fc / 4) / BLK; ++i) {   // 10 float4 per thread
            const int idx = t + i * BLK;
            const int row = idx >> 5;        // 32 float4 per 128-f row
            const int f4  = idx & 31;
            const float4 v = xg[idx];
            const unsigned lo = (unsigned)f2bf(v.x) | ((unsigned)f2bf(v.y) << 16);
            const unsigned hi = (unsigned)f2bf(v.z) | ((unsigned)f2bf(v.w) << 16);
            const int byt = (f4 * 8) ^ ((row & 7) << 4);    // XOR swizzle, keeps 8B alignment
            *reinterpret_cast<uint2*>(smem + row * 256 + byt) = make_uint2(lo, hi);
        }
        const float4* wg = reinterpret_cast<const float4*>(wt_ws);
#pragma unroll
        for (int i = 0; i < 4; ++i)
            *reinterpret_cast<float4*>(smem + WT_OFF + t * 16 + i * 4096) = wg[t + i * BLK];
    }
    __syncthreads();

    // ---- phase B: MFMA  hw[rows 80][cols 64] = x_bf16 . Wt^T ----
    const int w  = t >> 6;    // wave id -> col-tile
    const int l  = t & 63;
    const int lr = l & 15;    // row (A) / col (B) within tile
    const int lk = l >> 4;    // k sub-block (8 contiguous k each)

    bf16x8 bfrag[4];
    {
        const int c = w * 16 + lr;
        const char* wrow = smem + WT_OFF + c * 256;
        const int sw = (c & 7) << 4;
#pragma unroll
        for (int kc = 0; kc < 4; ++kc)
            bfrag[kc] = *reinterpret_cast<const bf16x8*>(wrow + ((kc * 64 + lk * 16) ^ sw));
    }

    f32x4 acc[MT];
#pragma unroll
    for (int m = 0; m < MT; ++m) acc[m] = (f32x4){0.f, 0.f, 0.f, 0.f};

#pragma unroll
    for (int m = 0; m < MT; ++m) {
        const int row = m * 16 + lr;
        const char* xrow = smem + row * 256;
        const int sw = (row & 7) << 4;
#pragma unroll
        for (int kc = 0; kc < 4; ++kc) {
            const bf16x8 af = *reinterpret_cast<const bf16x8*>(xrow + ((kc * 64 + lk * 16) ^ sw));
            acc[m] = __builtin_amdgcn_mfma_f32_16x16x32_bf16(af, bfrag[kc], acc[m], 0, 0, 0);
        }
    }
    __syncthreads();   // xl dead beyond this point

    // ---- phase C: acc -> hw LDS [80][68] f32 ----
    {
        float* hw = reinterpret_cast<float*>(smem);
        const int col = w * 16 + lr;
#pragma unroll
        for (int m = 0; m < MT; ++m) {
            const int rbase = m * 16 + lk * 4;
#pragma unroll
            for (int r = 0; r < 4; ++r)
                hw[(rbase + r) * 68 + col] = acc[m][r];
        }
    }
    __syncthreads();

    // ---- phase D: softmax over K=10 + leaky relu, thread = (node, head) ----
    const float* hw = reinterpret_cast<const float*>(smem);
    float* ol = reinterpret_cast<float*>(smem + OL_OFF);
    if (t < NPB * Hc) {   // 128 active
        const int h  = t & 15;
        const int ln = t >> 4;
        const float ar0 = a[0 * Hc + h];
        const float ar1 = a[1 * Hc + h];
        const float ar2 = a[2 * Hc + h];
        const float ar3 = a[3 * Hc + h];

        float4 hv[Kc];
        float  lg[Kc];
        float  mx = -1e30f;
#pragma unroll
        for (int k = 0; k < Kc; ++k) {
            hv[k] = *reinterpret_cast<const float4*>(hw + (ln * Kc + k) * 68 + h * 4);
            lg[k] = fmaf(hv[k].x, ar0, fmaf(hv[k].y, ar1, fmaf(hv[k].z, ar2, hv[k].w * ar3)));
            mx = fmaxf(mx, lg[k]);
        }
        float lsum = 0.f, o0 = 0.f, o1 = 0.f, o2 = 0.f, o3 = 0.f;
#pragma unroll
        for (int k = 0; k < Kc; ++k) {
            const float p = __expf(lg[k] - mx);
            lsum += p;
            o0 = fmaf(p, hv[k].x, o0);
            o1 = fmaf(p, hv[k].y, o1);
            o2 = fmaf(p, hv[k].z, o2);
            o3 = fmaf(p, hv[k].w, o3);
        }
        const float inv = 1.f / lsum;
        o0 *= inv; o1 *= inv; o2 *= inv; o3 *= inv;
        o0 = fmaxf(o0, 0.2f * o0);
        o1 = fmaxf(o1, 0.2f * o1);
        o2 = fmaxf(o2, 0.2f * o2);
        o3 = fmaxf(o3, 0.2f * o3);
        *reinterpret_cast<float4*>(ol + ln * 68 + h * 4) = make_float4(o0, o1, o2, o3);
    }
    __syncthreads();

    // ---- store transposed [B, 64, N], coalesced float4 ----
    if (t < 128) {
        const int c  = t >> 1;   // channel 0..63
        const int nq = t & 1;    // node quad
        const int nb = blockIdx.x * NPB;
        const int b  = nb / Nc;
        const int n0 = nb - b * Nc;
        float4 v;
        v.x = ol[(nq * 4 + 0) * 68 + c];
        v.y = ol[(nq * 4 + 1) * 68 + c];
        v.z = ol[(nq * 4 + 2) * 68 + c];
        v.w = ol[(nq * 4 + 3) * 68 + c];
        *reinterpret_cast<float4*>(out + ((size_t)b * Cc + c) * Nc + n0 + nq * 4) = v;
    }
}

extern "C" void kernel_launch(void* const* d_in, const int* in_sizes, int n_in,
                              void* d_out, int out_size, void* d_ws, size_t ws_size,
                              hipStream_t stream) {
    const float* x = (const float*)d_in[0];
    const float* W = (const float*)d_in[1];
    const float* a = (const float*)d_in[2];
    float* out = (float*)d_out;
    unsigned short* wt = (unsigned short*)d_ws;   // 16 KB used

    prep_w<<<1, 256, 0, stream>>>(W, wt);
    gat_kernel<<<NODES / NPB, BLK, 0, stream>>>(x, wt, a, out);
}